// Round 3
// baseline (1522.971 us; speedup 1.0000x reference)
//
#include <hip/hip_runtime.h>

#define NV 50000
#define NE 5000
#define NC 16
#define TAU_INV 2.0f
#define EPS 1e-8f
#define VCHUNK 1000
#define NCHUNK 50    // NV / VCHUNK
#define NLANE 5120   // 20 blocks x 256 threads (>= NE)
#define CAP 64       // max nonzeros per (edge, 1000-v chunk); E[nz]=20, +10 sigma safe

// ---------------- softmax: one thread per row, handles both pred_s and pred_t.
// Output layout: p[v][32] = [softmax(pred_s[v]) (16) | softmax(pred_t[v]) (16)]
__global__ __launch_bounds__(256) void softmax_kernel(
    const float* __restrict__ pred_s, const float* __restrict__ pred_t,
    float* __restrict__ p) {
  int i = blockIdx.x * 256 + threadIdx.x;
  if (i >= 2 * NV) return;
  const float* src;
  float* dst;
  if (i < NV) { src = pred_s + (size_t)i * NC; dst = p + (size_t)i * 32; }
  else        { int j = i - NV; src = pred_t + (size_t)j * NC; dst = p + (size_t)j * 32 + 16; }
  float4 a = ((const float4*)src)[0];
  float4 b = ((const float4*)src)[1];
  float4 c = ((const float4*)src)[2];
  float4 d = ((const float4*)src)[3];
  float x[16] = {a.x,a.y,a.z,a.w, b.x,b.y,b.z,b.w, c.x,c.y,c.z,c.w, d.x,d.y,d.z,d.w};
  float mx = x[0];
#pragma unroll
  for (int k = 1; k < 16; ++k) mx = fmaxf(mx, x[k]);
  float sum = 0.f;
#pragma unroll
  for (int k = 0; k < 16; ++k) { x[k] = expf(x[k] - mx); sum += x[k]; }
  float inv = 1.f / sum;
#pragma unroll
  for (int k = 0; k < 16; ++k) x[k] *= inv;
  float4 o0 = {x[0], x[1], x[2], x[3]};
  float4 o1 = {x[4], x[5], x[6], x[7]};
  float4 o2 = {x[8], x[9], x[10], x[11]};
  float4 o3 = {x[12], x[13], x[14], x[15]};
  ((float4*)dst)[0] = o0;
  ((float4*)dst)[1] = o1;
  ((float4*)dst)[2] = o2;
  ((float4*)dst)[3] = o3;
}

// ---------------- Phase A: stream H (the 1 GB), compact nonzero v-indices.
// H is exactly binary (0.0/1.0) per setup, ~2% dense. Only h loads in the
// loop -> unroll 8 keeps 8 HBM loads in flight per wave (2 KB), fully
// latency-hidden. nz layout: nz[(y*CAP + j)*NLANE + te] (lane-coalesced).
__global__ __launch_bounds__(256, 4) void sparsify_kernel(
    const float* __restrict__ H, int* __restrict__ nz, int* __restrict__ cnts) {
  int te = blockIdx.x * 256 + threadIdx.x;   // 0..NLANE-1
  int e = te < NE ? te : NE - 1;             // clamp; dup lanes predicated off in B
  int y = blockIdx.y;
  int v0 = y * VCHUNK;
  const float* __restrict__ hp = H + (size_t)v0 * NE + e;
  int* __restrict__ mybuf = nz + (size_t)y * CAP * NLANE + te;
  int cnt = 0;
  for (int vb = 0; vb < VCHUNK; vb += 8) {
    float h[8];
#pragma unroll
    for (int u = 0; u < 8; ++u) h[u] = hp[(size_t)(vb + u) * NE];
#pragma unroll
    for (int u = 0; u < 8; ++u) {
      if (h[u] != 0.0f && cnt < CAP) {
        mybuf[(size_t)cnt * NLANE] = v0 + vb + u;
        cnt++;
      }
    }
  }
  cnts[y * NLANE + te] = cnt;
}

// ---------------- Phase B: per (edge, chunk), sum p rows over nonzeros.
// h==1 exactly -> pure adds; deg contribution = cnt.
// acc layout (floats): deg[NE] | S[16][NE] | T[16][NE]
__global__ __launch_bounds__(256, 4) void gather_kernel(
    const int* __restrict__ nz, const int* __restrict__ cnts,
    const float* __restrict__ p, float* __restrict__ acc) {
  int te = blockIdx.x * 256 + threadIdx.x;
  int y = blockIdx.y;
  int cnt = (te < NE) ? cnts[y * NLANE + te] : 0;
  const int* __restrict__ mybuf = nz + (size_t)y * CAP * NLANE + te;

  float as[16], at[16];
#pragma unroll
  for (int k = 0; k < 16; ++k) { as[k] = 0.f; at[k] = 0.f; }

  for (int j = 0; j < cnt; ++j) {
    int v = mybuf[(size_t)j * NLANE];
    const float4* __restrict__ r = (const float4*)(p + (size_t)v * 32);
    float4 sA = r[0], sB = r[1], sC = r[2], sD = r[3];
    float4 tA = r[4], tB = r[5], tC = r[6], tD = r[7];
    as[0] += sA.x;  as[1] += sA.y;  as[2] += sA.z;  as[3] += sA.w;
    as[4] += sB.x;  as[5] += sB.y;  as[6] += sB.z;  as[7] += sB.w;
    as[8] += sC.x;  as[9] += sC.y;  as[10] += sC.z; as[11] += sC.w;
    as[12] += sD.x; as[13] += sD.y; as[14] += sD.z; as[15] += sD.w;
    at[0] += tA.x;  at[1] += tA.y;  at[2] += tA.z;  at[3] += tA.w;
    at[4] += tB.x;  at[5] += tB.y;  at[6] += tB.z;  at[7] += tB.w;
    at[8] += tC.x;  at[9] += tC.y;  at[10] += tC.z; at[11] += tC.w;
    at[12] += tD.x; at[13] += tD.y; at[14] += tD.z; at[15] += tD.w;
  }

  if (te < NE) {
    atomicAdd(&acc[te], (float)cnt);
#pragma unroll
    for (int k = 0; k < 16; ++k)
      atomicAdd(&acc[NE + (size_t)k * NE + te], as[k]);
#pragma unroll
    for (int k = 0; k < 16; ++k)
      atomicAdd(&acc[(size_t)17 * NE + (size_t)k * NE + te], at[k]);
  }
}

// ---------------- per-edge KL + masked reduction (single block, 256 threads)
__global__ __launch_bounds__(256) void kl_kernel(
    const float* __restrict__ acc, const unsigned char* __restrict__ e_mask,
    float* __restrict__ out) {
  __shared__ float snum[4];
  __shared__ float scnt[4];
  int t = threadIdx.x;
  float num = 0.f, cnt = 0.f;
  for (int e = t; e < NE; e += 256) {
    if (e_mask[e]) {
      float deg = acc[e];
      float invd = 1.f / deg;
      float kl = 0.f;
#pragma unroll
      for (int k = 0; k < 16; ++k) {
        float ms = acc[NE + (size_t)k * NE + e] * invd;
        float mt = acc[(size_t)17 * NE + (size_t)k * NE + e] * invd;
        float xs = ms * TAU_INV + EPS;
        float xt = mt * TAU_INV + EPS;
        kl += xt * (logf(xt) - logf(xs));
      }
      num += kl;
      cnt += 1.f;
    }
  }
#pragma unroll
  for (int off = 32; off > 0; off >>= 1) {
    num += __shfl_down(num, off, 64);
    cnt += __shfl_down(cnt, off, 64);
  }
  if ((t & 63) == 0) { snum[t >> 6] = num; scnt[t >> 6] = cnt; }
  __syncthreads();
  if (t == 0) {
    float n = snum[0] + snum[1] + snum[2] + snum[3];
    float c2 = scnt[0] + scnt[1] + scnt[2] + scnt[3];
    out[0] = n / fmaxf(c2, 1.f);
  }
}

extern "C" void kernel_launch(void* const* d_in, const int* in_sizes, int n_in,
                              void* d_out, int out_size, void* d_ws, size_t ws_size,
                              hipStream_t stream) {
  const float* pred_s = (const float*)d_in[0];
  const float* pred_t = (const float*)d_in[1];
  const float* H      = (const float*)d_in[2];
  const unsigned char* e_mask = (const unsigned char*)d_in[3];

  float* ws  = (float*)d_ws;
  float* p   = ws;                                   // NV*32 floats (6.4 MB)
  float* acc = ws + (size_t)NV * 32;                 // 33*NE floats (660 KB)
  int*  cnts = (int*)(acc + (size_t)33 * NE);        // NCHUNK*NLANE ints (1 MB)
  int*  nz   = cnts + (size_t)NCHUNK * NLANE;        // NCHUNK*CAP*NLANE ints (65.5 MB)

  hipMemsetAsync(acc, 0, (size_t)33 * NE * sizeof(float), stream);
  softmax_kernel<<<dim3((2 * NV + 255) / 256), 256, 0, stream>>>(pred_s, pred_t, p);
  sparsify_kernel<<<dim3(NLANE / 256, NCHUNK), 256, 0, stream>>>(H, nz, cnts);
  gather_kernel<<<dim3(NLANE / 256, NCHUNK), 256, 0, stream>>>(nz, cnts, p, acc);
  kl_kernel<<<1, 256, 0, stream>>>(acc, e_mask, (float*)d_out);
}

// Round 4
// 1428.097 us; speedup vs baseline: 1.0664x; 1.0664x over previous
//
#include <hip/hip_runtime.h>

#define NV 50000
#define NE 5000
#define NC 16
#define TAU_INV 2.0f
#define EPS 1e-8f

#define NLANE 5120      // 5 x-blocks * 1024 edge slots
#define EBLK 1024       // edges per x-block (4 per lane * 256 threads)
#define NXB 5
#define NCH 100         // v-chunks
#define VCH 500         // NV / NCH

// ---------------- softmax: one thread per row, both pred_s and pred_t.
// Output layout: p[v][32] = [softmax(pred_s[v]) (16) | softmax(pred_t[v]) (16)]
__global__ __launch_bounds__(256) void softmax_kernel(
    const float* __restrict__ pred_s, const float* __restrict__ pred_t,
    float* __restrict__ p) {
  int i = blockIdx.x * 256 + threadIdx.x;
  if (i >= 2 * NV) return;
  const float* src;
  float* dst;
  if (i < NV) { src = pred_s + (size_t)i * NC; dst = p + (size_t)i * 32; }
  else        { int j = i - NV; src = pred_t + (size_t)j * NC; dst = p + (size_t)j * 32 + 16; }
  float4 a = ((const float4*)src)[0];
  float4 b = ((const float4*)src)[1];
  float4 c = ((const float4*)src)[2];
  float4 d = ((const float4*)src)[3];
  float x[16] = {a.x,a.y,a.z,a.w, b.x,b.y,b.z,b.w, c.x,c.y,c.z,c.w, d.x,d.y,d.z,d.w};
  float mx = x[0];
#pragma unroll
  for (int k = 1; k < 16; ++k) mx = fmaxf(mx, x[k]);
  float sum = 0.f;
#pragma unroll
  for (int k = 0; k < 16; ++k) { x[k] = expf(x[k] - mx); sum += x[k]; }
  float inv = 1.f / sum;
#pragma unroll
  for (int k = 0; k < 16; ++k) x[k] *= inv;
  float4 o0 = {x[0], x[1], x[2], x[3]};
  float4 o1 = {x[4], x[5], x[6], x[7]};
  float4 o2 = {x[8], x[9], x[10], x[11]};
  float4 o3 = {x[12], x[13], x[14], x[15]};
  ((float4*)dst)[0] = o0;
  ((float4*)dst)[1] = o1;
  ((float4*)dst)[2] = o2;
  ((float4*)dst)[3] = o3;
}

// ---------------- main accumulation: 4 edges per lane (float4 H loads,
// 1 KB contiguous per wave per row), h-prefetch 4 rows deep, NO atomics:
// per-(xb,y) float4 partial stores to a private slice.
// part layout (floats): part[y][k][NLANE], k: 0..15 = S, 16..31 = T, 32 = deg
__global__ __launch_bounds__(256, 2) void accum_kernel(
    const float* __restrict__ H, const float* __restrict__ p,
    float* __restrict__ part) {
  int xb = blockIdx.x;
  int y  = blockIdx.y;
  int e0 = xb * EBLK + 4 * (int)threadIdx.x;
  if (e0 > NE - 4) e0 = NE - 4;   // clamped lanes duplicate edge 4996..4999:
                                  // identical values -> benign duplicate store
  int v0 = y * VCH;

  float4 aS[16], aT[16], dg;
#pragma unroll
  for (int k = 0; k < 16; ++k) {
    aS[k] = make_float4(0.f, 0.f, 0.f, 0.f);
    aT[k] = make_float4(0.f, 0.f, 0.f, 0.f);
  }
  dg = make_float4(0.f, 0.f, 0.f, 0.f);

  const float* __restrict__ hbase = H + (size_t)v0 * NE + e0;
  const float* __restrict__ pbase = p + (size_t)v0 * 32;

  float4 hc[4];
#pragma unroll
  for (int u = 0; u < 4; ++u)
    hc[u] = *(const float4*)(hbase + (size_t)u * NE);

  for (int vb = 0; vb < VCH; vb += 4) {
    // prefetch next 4 H rows (clamped re-load on last iter; in-bounds, benign)
    int nb = (vb + 4 < VCH) ? vb + 4 : vb;
    float4 hn[4];
#pragma unroll
    for (int u = 0; u < 4; ++u)
      hn[u] = *(const float4*)(hbase + (size_t)(nb + u) * NE);

#pragma unroll
    for (int u = 0; u < 4; ++u) {
      const float4* __restrict__ r = (const float4*)(pbase + (size_t)(vb + u) * 32);
      float4 s0 = r[0], s1 = r[1], s2 = r[2], s3 = r[3];
      float4 t0 = r[4], t1 = r[5], t2 = r[6], t3 = r[7];
      float4 h = hc[u];
      dg.x += h.x; dg.y += h.y; dg.z += h.z; dg.w += h.w;
      float sv[16] = {s0.x,s0.y,s0.z,s0.w, s1.x,s1.y,s1.z,s1.w,
                      s2.x,s2.y,s2.z,s2.w, s3.x,s3.y,s3.z,s3.w};
      float tv[16] = {t0.x,t0.y,t0.z,t0.w, t1.x,t1.y,t1.z,t1.w,
                      t2.x,t2.y,t2.z,t2.w, t3.x,t3.y,t3.z,t3.w};
#pragma unroll
      for (int k = 0; k < 16; ++k) {
        aS[k].x = fmaf(h.x, sv[k], aS[k].x);
        aS[k].y = fmaf(h.y, sv[k], aS[k].y);
        aS[k].z = fmaf(h.z, sv[k], aS[k].z);
        aS[k].w = fmaf(h.w, sv[k], aS[k].w);
        aT[k].x = fmaf(h.x, tv[k], aT[k].x);
        aT[k].y = fmaf(h.y, tv[k], aT[k].y);
        aT[k].z = fmaf(h.z, tv[k], aT[k].z);
        aT[k].w = fmaf(h.w, tv[k], aT[k].w);
      }
    }
#pragma unroll
    for (int u = 0; u < 4; ++u) hc[u] = hn[u];
  }

  float* op = part + (size_t)y * 33 * NLANE + e0;
#pragma unroll
  for (int k = 0; k < 16; ++k)
    *(float4*)(op + (size_t)k * NLANE) = aS[k];
#pragma unroll
  for (int k = 0; k < 16; ++k)
    *(float4*)(op + (size_t)(16 + k) * NLANE) = aT[k];
  *(float4*)(op + (size_t)32 * NLANE) = dg;
}

// ---------------- reduce the NCH partials: acc[k][NLANE] = sum_y part[y][k][NLANE]
__global__ __launch_bounds__(256) void reduce_kernel(
    const float* __restrict__ part, float* __restrict__ acc) {
  int i = blockIdx.x * 256 + threadIdx.x;
  if (i >= 33 * NLANE) return;
  float s = 0.f;
#pragma unroll 4
  for (int y = 0; y < NCH; ++y) s += part[(size_t)y * 33 * NLANE + i];
  acc[i] = s;
}

// ---------------- per-edge KL + masked reduction (single block, 256 threads)
// acc layout: acc[k*NLANE + e]; S at k, T at 16+k, deg at 32
__global__ __launch_bounds__(256) void kl_kernel(
    const float* __restrict__ acc, const unsigned char* __restrict__ e_mask,
    float* __restrict__ out) {
  __shared__ float snum[4];
  __shared__ float scnt[4];
  int t = threadIdx.x;
  float num = 0.f, cnt = 0.f;
  for (int e = t; e < NE; e += 256) {
    if (e_mask[e]) {
      float deg = acc[(size_t)32 * NLANE + e];
      float invd = 1.f / deg;
      float kl = 0.f;
#pragma unroll
      for (int k = 0; k < 16; ++k) {
        float ms = acc[(size_t)k * NLANE + e] * invd;
        float mt = acc[(size_t)(16 + k) * NLANE + e] * invd;
        float xs = ms * TAU_INV + EPS;
        float xt = mt * TAU_INV + EPS;
        kl += xt * (logf(xt) - logf(xs));
      }
      num += kl;
      cnt += 1.f;
    }
  }
#pragma unroll
  for (int off = 32; off > 0; off >>= 1) {
    num += __shfl_down(num, off, 64);
    cnt += __shfl_down(cnt, off, 64);
  }
  if ((t & 63) == 0) { snum[t >> 6] = num; scnt[t >> 6] = cnt; }
  __syncthreads();
  if (t == 0) {
    float n = snum[0] + snum[1] + snum[2] + snum[3];
    float c2 = scnt[0] + scnt[1] + scnt[2] + scnt[3];
    out[0] = n / fmaxf(c2, 1.f);
  }
}

extern "C" void kernel_launch(void* const* d_in, const int* in_sizes, int n_in,
                              void* d_out, int out_size, void* d_ws, size_t ws_size,
                              hipStream_t stream) {
  const float* pred_s = (const float*)d_in[0];
  const float* pred_t = (const float*)d_in[1];
  const float* H      = (const float*)d_in[2];
  const unsigned char* e_mask = (const unsigned char*)d_in[3];

  float* ws   = (float*)d_ws;
  float* p    = ws;                                    // NV*32       (6.40 MB)
  float* acc  = ws + (size_t)NV * 32;                  // 33*NLANE    (0.68 MB)
  float* part = acc + (size_t)33 * NLANE;              // NCH*33*NLANE (67.6 MB)

  softmax_kernel<<<dim3((2 * NV + 255) / 256), 256, 0, stream>>>(pred_s, pred_t, p);
  accum_kernel<<<dim3(NXB, NCH), 256, 0, stream>>>(H, p, part);
  reduce_kernel<<<dim3((33 * NLANE + 255) / 256), 256, 0, stream>>>(part, acc);
  kl_kernel<<<1, 256, 0, stream>>>(acc, e_mask, (float*)d_out);
}